// Round 1
// baseline (143.645 us; speedup 1.0000x reference)
//
#include <hip/hip_runtime.h>
#include <stdint.h>

#define NROWS 4096
#define DIM   512
#define EPS_COS 1e-8f
#define EPS_W   1e-6f

typedef unsigned short ushort_t;
typedef __attribute__((ext_vector_type(8))) short   short8;
typedef __attribute__((ext_vector_type(8))) unsigned short ushort8;
typedef __attribute__((ext_vector_type(4))) float   floatx4;

// ---------- helpers ----------
__device__ inline ushort_t f2bf(float x) {            // RNE float->bf16
    unsigned u = __float_as_uint(x);
    unsigned r = (u + 0x7FFFu + ((u >> 16) & 1u)) >> 16;
    return (ushort_t)r;
}
// monotone float<->uint mapping for atomicMin/Max on floats
__device__ inline unsigned fmap(float f) {
    unsigned u = __float_as_uint(f);
    return (u & 0x80000000u) ? ~u : (u | 0x80000000u);
}
__device__ inline float funmap(unsigned u) {
    return __uint_as_float((u & 0x80000000u) ? (u & 0x7fffffffu) : ~u);
}

__device__ inline void gload_lds16(const void* g, void* l) {
    auto* gp = reinterpret_cast<const __attribute__((address_space(1))) unsigned int*>(
        reinterpret_cast<uintptr_t>(g));
    auto* lp = reinterpret_cast<__attribute__((address_space(3))) unsigned int*>(
        reinterpret_cast<uintptr_t>(l));
    __builtin_amdgcn_global_load_lds(gp, lp, 16, 0, 0);
}

// stage a 128x64 bf16 tile: linear LDS dest + inverse-swizzled global source.
// LDS[r][c_phys] holds logical chunk c_phys ^ (r&7)  (chunks = 16B = 8 bf16)
__device__ inline void stage_tile(const ushort_t* __restrict__ gbase, // tile row0, k0 applied
                                  ushort_t* lds, int wave, int lane) {
#pragma unroll
    for (int q = 0; q < 4; q++) {
        int row0 = wave * 32 + q * 8;                 // multiple of 8
        int lrow = row0 + (lane >> 3);
        int src_chunk = (lane & 7) ^ (lane >> 3);     // (lane&7) ^ (lrow&7)
        const ushort_t* g = gbase + (size_t)lrow * DIM + src_chunk * 8;
        ushort_t* l = lds + row0 * 64;                // wave-uniform base; HW adds lane*16
        gload_lds16(g, l);
    }
}

// fragment read (A and B share the same pattern for row-major-stored operands):
// lane l -> row = frag_row*16 + (l&15), logical chunk = kk*4 + (l>>4), phys = chunk ^ (row&7)
__device__ inline short8 read_frag(const ushort_t* tile, int frag_row, int kk, int lane) {
    int r = frag_row * 16 + (lane & 15);
    int c = (kk * 4 + (lane >> 4)) ^ (lane & 7);
    return *reinterpret_cast<const short8*>(tile + r * 64 + c * 8);
}

// ---------- kernel 1: convert + norms + init ----------
__global__ __launch_bounds__(256) void prep_kernel(
    const float* __restrict__ img, const float* __restrict__ txt,
    ushort_t* __restrict__ Ibf, ushort_t* __restrict__ Tbf,
    float* __restrict__ img_norm, float* __restrict__ txt_norm,
    unsigned* __restrict__ mn_u, unsigned* __restrict__ mx_u) {
    const int wave = threadIdx.x >> 6, lane = threadIdx.x & 63;
    const int row = blockIdx.x * 4 + wave;
    const int col0 = lane * 8;
    {
        const float4* p = reinterpret_cast<const float4*>(img + (size_t)row * DIM + col0);
        float4 a = p[0], b = p[1];
        float ss = a.x*a.x + a.y*a.y + a.z*a.z + a.w*a.w
                 + b.x*b.x + b.y*b.y + b.z*b.z + b.w*b.w;
        ushort8 o;
        o[0]=f2bf(a.x); o[1]=f2bf(a.y); o[2]=f2bf(a.z); o[3]=f2bf(a.w);
        o[4]=f2bf(b.x); o[5]=f2bf(b.y); o[6]=f2bf(b.z); o[7]=f2bf(b.w);
        *reinterpret_cast<ushort8*>(Ibf + (size_t)row * DIM + col0) = o;
#pragma unroll
        for (int s = 1; s < 64; s <<= 1) ss += __shfl_xor(ss, s);
        if (lane == 0) img_norm[row] = sqrtf(ss);
    }
    {
        const float4* p = reinterpret_cast<const float4*>(txt + (size_t)row * DIM + col0);
        float4 a = p[0], b = p[1];
        float ss = a.x*a.x + a.y*a.y + a.z*a.z + a.w*a.w
                 + b.x*b.x + b.y*b.y + b.z*b.z + b.w*b.w;
        ushort8 o;
        o[0]=f2bf(a.x); o[1]=f2bf(a.y); o[2]=f2bf(a.z); o[3]=f2bf(a.w);
        o[4]=f2bf(b.x); o[5]=f2bf(b.y); o[6]=f2bf(b.z); o[7]=f2bf(b.w);
        *reinterpret_cast<ushort8*>(Tbf + (size_t)row * DIM + col0) = o;
#pragma unroll
        for (int s = 1; s < 64; s <<= 1) ss += __shfl_xor(ss, s);
        if (lane == 0) txt_norm[row] = sqrtf(ss);
    }
    if (lane == 0) { mn_u[row] = 0xFFFFFFFFu; mx_u[row] = 0u; }
}

// ---------- kernel 2: T.T^T row min/max ----------
__global__ __launch_bounds__(256) void phase1_kernel(
    const ushort_t* __restrict__ Tbf,
    unsigned* __restrict__ mn_u, unsigned* __restrict__ mx_u) {
    __shared__ __align__(16) ushort_t Ti[128 * 64];
    __shared__ __align__(16) ushort_t Tj[128 * 64];
    const int tile_j = blockIdx.x, tile_i = blockIdx.y;
    const int wave = threadIdx.x >> 6, lane = threadIdx.x & 63;
    const int wr = wave >> 1, wc = wave & 1;

    floatx4 acc[4][4];
#pragma unroll
    for (int m = 0; m < 4; m++)
#pragma unroll
        for (int n = 0; n < 4; n++) acc[m][n] = (floatx4){0.f, 0.f, 0.f, 0.f};

    for (int k0 = 0; k0 < DIM; k0 += 64) {
        __syncthreads();
        stage_tile(Tbf + (size_t)(tile_i * 128) * DIM + k0, Ti, wave, lane);
        stage_tile(Tbf + (size_t)(tile_j * 128) * DIM + k0, Tj, wave, lane);
        __syncthreads();
#pragma unroll
        for (int kk = 0; kk < 2; kk++) {
            short8 a[4], b[4];
#pragma unroll
            for (int m = 0; m < 4; m++) a[m] = read_frag(Ti, wr * 4 + m, kk, lane);
#pragma unroll
            for (int n = 0; n < 4; n++) b[n] = read_frag(Tj, wc * 4 + n, kk, lane);
#pragma unroll
            for (int m = 0; m < 4; m++)
#pragma unroll
                for (int n = 0; n < 4; n++)
                    acc[m][n] = __builtin_amdgcn_mfma_f32_16x16x32_bf16(a[m], b[n], acc[m][n], 0, 0, 0);
        }
    }

    // per-row min/max: reg dim is row; cols live across n-frags and lanes&15
#pragma unroll
    for (int m = 0; m < 4; m++) {
        float mn4[4], mx4[4];
#pragma unroll
        for (int reg = 0; reg < 4; reg++) {
            float vmin = acc[m][0][reg], vmax = acc[m][0][reg];
#pragma unroll
            for (int n = 1; n < 4; n++) {
                vmin = fminf(vmin, acc[m][n][reg]);
                vmax = fmaxf(vmax, acc[m][n][reg]);
            }
#pragma unroll
            for (int s = 1; s < 16; s <<= 1) {
                vmin = fminf(vmin, __shfl_xor(vmin, s));
                vmax = fmaxf(vmax, __shfl_xor(vmax, s));
            }
            mn4[reg] = vmin; mx4[reg] = vmax;
        }
        if ((lane & 15) == 0) {
            int g = lane >> 4;
#pragma unroll
            for (int reg = 0; reg < 4; reg++) {
                int row_g = tile_i * 128 + wr * 64 + m * 16 + g * 4 + reg;
                atomicMin(&mn_u[row_g], fmap(mn4[reg]));
                atomicMax(&mx_u[row_g], fmap(mx4[reg]));
            }
        }
    }
}

// ---------- kernel 3: dots + sim + loss ----------
__global__ __launch_bounds__(256) void phase2_kernel(
    const ushort_t* __restrict__ Ibf, const ushort_t* __restrict__ Tbf,
    const float* __restrict__ img_norm, const float* __restrict__ txt_norm,
    const unsigned* __restrict__ mn_u, const unsigned* __restrict__ mx_u,
    const int* __restrict__ instr, float* __restrict__ out) {
    __shared__ __align__(16) ushort_t Im[128 * 64];
    __shared__ __align__(16) ushort_t Ti[128 * 64];
    __shared__ __align__(16) ushort_t Tj[128 * 64];
    const int tile_j = blockIdx.x, tile_i = blockIdx.y;
    const int wave = threadIdx.x >> 6, lane = threadIdx.x & 63;
    const int wr = wave >> 1, wc = wave & 1;

    floatx4 accD[4][4], accS[4][4];
#pragma unroll
    for (int m = 0; m < 4; m++)
#pragma unroll
        for (int n = 0; n < 4; n++) {
            accD[m][n] = (floatx4){0.f, 0.f, 0.f, 0.f};
            accS[m][n] = (floatx4){0.f, 0.f, 0.f, 0.f};
        }

    for (int k0 = 0; k0 < DIM; k0 += 64) {
        __syncthreads();
        stage_tile(Ibf + (size_t)(tile_i * 128) * DIM + k0, Im, wave, lane);
        stage_tile(Tbf + (size_t)(tile_i * 128) * DIM + k0, Ti, wave, lane);
        stage_tile(Tbf + (size_t)(tile_j * 128) * DIM + k0, Tj, wave, lane);
        __syncthreads();
#pragma unroll
        for (int kk = 0; kk < 2; kk++) {
            short8 ai[4], at[4], b[4];
#pragma unroll
            for (int m = 0; m < 4; m++) ai[m] = read_frag(Im, wr * 4 + m, kk, lane);
#pragma unroll
            for (int m = 0; m < 4; m++) at[m] = read_frag(Ti, wr * 4 + m, kk, lane);
#pragma unroll
            for (int n = 0; n < 4; n++) b[n] = read_frag(Tj, wc * 4 + n, kk, lane);
#pragma unroll
            for (int m = 0; m < 4; m++)
#pragma unroll
                for (int n = 0; n < 4; n++) {
                    accD[m][n] = __builtin_amdgcn_mfma_f32_16x16x32_bf16(ai[m], b[n], accD[m][n], 0, 0, 0);
                    accS[m][n] = __builtin_amdgcn_mfma_f32_16x16x32_bf16(at[m], b[n], accS[m][n], 0, 0, 0);
                }
        }
    }

    // epilogue: per-pair loss
    const int rbase0 = tile_i * 128 + wr * 64;
    const int cbase0 = tile_j * 128 + wc * 64;
    float tn4[4]; int ic4[4];
#pragma unroll
    for (int n = 0; n < 4; n++) {
        int col_g = cbase0 + n * 16 + (lane & 15);
        tn4[n] = txt_norm[col_g];
        ic4[n] = instr[col_g];
    }
    float lsum = 0.f;
#pragma unroll
    for (int m = 0; m < 4; m++) {
        int rb = rbase0 + m * 16 + (lane >> 4) * 4;
#pragma unroll
        for (int reg = 0; reg < 4; reg++) {
            int row_g = rb + reg;
            float inr = img_norm[row_g];
            float mnv = funmap(mn_u[row_g]);
            float mxv = funmap(mx_u[row_g]);
            int   ir  = instr[row_g];
            float winv = 1.0f / (mxv - mnv + EPS_W);
#pragma unroll
            for (int n = 0; n < 4; n++) {
                int col_g = cbase0 + n * 16 + (lane & 15);
                float cosv = accD[m][n][reg] / fmaxf(inr * tn4[n], EPS_COS);
                float w = (accS[m][n][reg] - mnv) * winv;
                bool aligned = (ir == ic4[n]) || (row_g == col_g);
                lsum += aligned ? (1.0f - cosv) : fmaxf(0.0f, cosv - w);
            }
        }
    }
#pragma unroll
    for (int s = 1; s < 64; s <<= 1) lsum += __shfl_xor(lsum, s);
    if (lane == 0)
        atomicAdd(out, lsum * (1.0f / ((float)NROWS * (float)NROWS)));
}

// ---------- launch ----------
extern "C" void kernel_launch(void* const* d_in, const int* in_sizes, int n_in,
                              void* d_out, int out_size, void* d_ws, size_t ws_size,
                              hipStream_t stream) {
    const float* img = (const float*)d_in[0];
    const float* txt = (const float*)d_in[1];
    const int* instr = (const int*)d_in[2];
    float* out = (float*)d_out;

    char* ws = (char*)d_ws;
    ushort_t* Tbf = (ushort_t*)ws;                                  // 4 MB
    ushort_t* Ibf = (ushort_t*)(ws + (size_t)NROWS * DIM * 2);      // 4 MB
    float* img_norm = (float*)(ws + (size_t)NROWS * DIM * 4);       // 16 KB
    float* txt_norm = img_norm + NROWS;                             // 16 KB
    unsigned* mn_u = (unsigned*)(txt_norm + NROWS);                 // 16 KB
    unsigned* mx_u = mn_u + NROWS;                                  // 16 KB

    hipMemsetAsync(d_out, 0, sizeof(float), stream);
    prep_kernel<<<NROWS / 4, 256, 0, stream>>>(img, txt, Ibf, Tbf,
                                               img_norm, txt_norm, mn_u, mx_u);
    dim3 grid(NROWS / 128, NROWS / 128);
    phase1_kernel<<<grid, 256, 0, stream>>>(Tbf, mn_u, mx_u);
    phase2_kernel<<<grid, 256, 0, stream>>>(Ibf, Tbf, img_norm, txt_norm,
                                            mn_u, mx_u, instr, out);
}

// Round 2
// 143.060 us; speedup vs baseline: 1.0041x; 1.0041x over previous
//
#include <hip/hip_runtime.h>
#include <stdint.h>

#define NROWS 4096
#define DIM   512
#define EPS_COS 1e-8f
#define EPS_W   1e-6f

typedef unsigned short ushort_t;
typedef __attribute__((ext_vector_type(8))) short   short8;
typedef __attribute__((ext_vector_type(8))) unsigned short ushort8;
typedef __attribute__((ext_vector_type(4))) float   floatx4;

// ---------- helpers ----------
__device__ inline ushort_t f2bf(float x) {            // RNE float->bf16
    unsigned u = __float_as_uint(x);
    unsigned r = (u + 0x7FFFu + ((u >> 16) & 1u)) >> 16;
    return (ushort_t)r;
}
__device__ inline float bf2f(ushort_t u) {
    return __uint_as_float(((unsigned)u) << 16);
}
// monotone float<->uint mapping for atomicMin/Max on floats
__device__ inline unsigned fmap(float f) {
    unsigned u = __float_as_uint(f);
    return (u & 0x80000000u) ? ~u : (u | 0x80000000u);
}
__device__ inline float funmap(unsigned u) {
    return __uint_as_float((u & 0x80000000u) ? (u & 0x7fffffffu) : ~u);
}

__device__ inline void gload_lds16(const void* g, void* l) {
    auto* gp = reinterpret_cast<const __attribute__((address_space(1))) unsigned int*>(
        reinterpret_cast<uintptr_t>(g));
    auto* lp = reinterpret_cast<__attribute__((address_space(3))) unsigned int*>(
        reinterpret_cast<uintptr_t>(l));
    __builtin_amdgcn_global_load_lds(gp, lp, 16, 0, 0);
}

// stage a 128x64 bf16 tile: linear LDS dest + inverse-swizzled global source.
// LDS[r][c_phys] holds logical chunk c_phys ^ (r&7)  (chunks = 16B = 8 bf16)
__device__ inline void stage_tile(const ushort_t* __restrict__ gbase, // tile row0, k0 applied
                                  ushort_t* lds, int wave, int lane) {
#pragma unroll
    for (int q = 0; q < 4; q++) {
        int row0 = wave * 32 + q * 8;                 // multiple of 8
        int lrow = row0 + (lane >> 3);
        int src_chunk = (lane & 7) ^ (lane >> 3);     // (lane&7) ^ (lrow&7)
        const ushort_t* g = gbase + (size_t)lrow * DIM + src_chunk * 8;
        ushort_t* l = lds + row0 * 64;                // wave-uniform base; HW adds lane*16
        gload_lds16(g, l);
    }
}

// fragment read: lane l -> row = frag_row*16 + (l&15), logical chunk = kk*4 + (l>>4),
// phys chunk = logical ^ (row&7)
__device__ inline short8 read_frag(const ushort_t* tile, int frag_row, int kk, int lane) {
    int r = frag_row * 16 + (lane & 15);
    int c = (kk * 4 + (lane >> 4)) ^ (lane & 7);
    return *reinterpret_cast<const short8*>(tile + r * 64 + c * 8);
}

// ---------- kernel 1: convert + norms + init ----------
__global__ __launch_bounds__(256) void prep_kernel(
    const float* __restrict__ img, const float* __restrict__ txt,
    ushort_t* __restrict__ Ibf, ushort_t* __restrict__ Tbf,
    float* __restrict__ img_norm, float* __restrict__ txt_norm,
    unsigned* __restrict__ mn_u, unsigned* __restrict__ mx_u) {
    const int wave = threadIdx.x >> 6, lane = threadIdx.x & 63;
    const int row = blockIdx.x * 4 + wave;
    const int col0 = lane * 8;
    {
        const float4* p = reinterpret_cast<const float4*>(img + (size_t)row * DIM + col0);
        float4 a = p[0], b = p[1];
        float ss = a.x*a.x + a.y*a.y + a.z*a.z + a.w*a.w
                 + b.x*b.x + b.y*b.y + b.z*b.z + b.w*b.w;
        ushort8 o;
        o[0]=f2bf(a.x); o[1]=f2bf(a.y); o[2]=f2bf(a.z); o[3]=f2bf(a.w);
        o[4]=f2bf(b.x); o[5]=f2bf(b.y); o[6]=f2bf(b.z); o[7]=f2bf(b.w);
        *reinterpret_cast<ushort8*>(Ibf + (size_t)row * DIM + col0) = o;
#pragma unroll
        for (int s = 1; s < 64; s <<= 1) ss += __shfl_xor(ss, s);
        if (lane == 0) img_norm[row] = sqrtf(ss);
    }
    {
        const float4* p = reinterpret_cast<const float4*>(txt + (size_t)row * DIM + col0);
        float4 a = p[0], b = p[1];
        float ss = a.x*a.x + a.y*a.y + a.z*a.z + a.w*a.w
                 + b.x*b.x + b.y*b.y + b.z*b.z + b.w*b.w;
        ushort8 o;
        o[0]=f2bf(a.x); o[1]=f2bf(a.y); o[2]=f2bf(a.z); o[3]=f2bf(a.w);
        o[4]=f2bf(b.x); o[5]=f2bf(b.y); o[6]=f2bf(b.z); o[7]=f2bf(b.w);
        *reinterpret_cast<ushort8*>(Tbf + (size_t)row * DIM + col0) = o;
#pragma unroll
        for (int s = 1; s < 64; s <<= 1) ss += __shfl_xor(ss, s);
        if (lane == 0) txt_norm[row] = sqrtf(ss);
    }
    if (lane == 0) { mn_u[row] = 0xFFFFFFFFu; mx_u[row] = 0u; }
}

// ---------- kernel 2: T.T^T -> row min/max atomics + packed bf16 sim store ----------
// sim is stored PER-LANE-PACKED: tile (i,j), thread t owns 64 values in its
// register layout; stored contiguously so phase2 (same decomposition) reads
// them back with coalesced 16B loads. element idx = m*16 + n*4 + reg.
__global__ __launch_bounds__(256, 4) void phase1_kernel(
    const ushort_t* __restrict__ Tbf,
    unsigned* __restrict__ mn_u, unsigned* __restrict__ mx_u,
    ushort_t* __restrict__ simbuf) {
    __shared__ __align__(16) ushort_t Ti[128 * 64];
    __shared__ __align__(16) ushort_t Tj[128 * 64];
    const int tile_j = blockIdx.x, tile_i = blockIdx.y;
    const int wave = threadIdx.x >> 6, lane = threadIdx.x & 63;
    const int wr = wave >> 1, wc = wave & 1;

    floatx4 acc[4][4];
#pragma unroll
    for (int m = 0; m < 4; m++)
#pragma unroll
        for (int n = 0; n < 4; n++) acc[m][n] = (floatx4){0.f, 0.f, 0.f, 0.f};

    for (int k0 = 0; k0 < DIM; k0 += 64) {
        __syncthreads();
        stage_tile(Tbf + (size_t)(tile_i * 128) * DIM + k0, Ti, wave, lane);
        stage_tile(Tbf + (size_t)(tile_j * 128) * DIM + k0, Tj, wave, lane);
        __syncthreads();
#pragma unroll
        for (int kk = 0; kk < 2; kk++) {
            short8 a[4], b[4];
#pragma unroll
            for (int m = 0; m < 4; m++) a[m] = read_frag(Ti, wr * 4 + m, kk, lane);
#pragma unroll
            for (int n = 0; n < 4; n++) b[n] = read_frag(Tj, wc * 4 + n, kk, lane);
#pragma unroll
            for (int m = 0; m < 4; m++)
#pragma unroll
                for (int n = 0; n < 4; n++)
                    acc[m][n] = __builtin_amdgcn_mfma_f32_16x16x32_bf16(a[m], b[n], acc[m][n], 0, 0, 0);
        }
    }

    // per-row min/max (fp32-exact)
#pragma unroll
    for (int m = 0; m < 4; m++) {
        float mn4[4], mx4[4];
#pragma unroll
        for (int reg = 0; reg < 4; reg++) {
            float vmin = acc[m][0][reg], vmax = acc[m][0][reg];
#pragma unroll
            for (int n = 1; n < 4; n++) {
                vmin = fminf(vmin, acc[m][n][reg]);
                vmax = fmaxf(vmax, acc[m][n][reg]);
            }
#pragma unroll
            for (int s = 1; s < 16; s <<= 1) {
                vmin = fminf(vmin, __shfl_xor(vmin, s));
                vmax = fmaxf(vmax, __shfl_xor(vmax, s));
            }
            mn4[reg] = vmin; mx4[reg] = vmax;
        }
        if ((lane & 15) == 0) {
            int g = lane >> 4;
#pragma unroll
            for (int reg = 0; reg < 4; reg++) {
                int row_g = tile_i * 128 + wr * 64 + m * 16 + g * 4 + reg;
                atomicMin(&mn_u[row_g], fmap(mn4[reg]));
                atomicMax(&mx_u[row_g], fmap(mx4[reg]));
            }
        }
    }

    // packed bf16 store of the sim tile (8 x 16B per lane, coalesced)
    ushort_t* sp = simbuf + (((size_t)(tile_i * 32 + tile_j) * 256 + threadIdx.x) * 64);
#pragma unroll
    for (int c = 0; c < 8; c++) {
        int m = c >> 1, n0 = (c & 1) * 2;
        ushort8 o;
        o[0] = f2bf(acc[m][n0][0]);     o[1] = f2bf(acc[m][n0][1]);
        o[2] = f2bf(acc[m][n0][2]);     o[3] = f2bf(acc[m][n0][3]);
        o[4] = f2bf(acc[m][n0 + 1][0]); o[5] = f2bf(acc[m][n0 + 1][1]);
        o[6] = f2bf(acc[m][n0 + 1][2]); o[7] = f2bf(acc[m][n0 + 1][3]);
        reinterpret_cast<ushort8*>(sp)[c] = o;
    }
}

// ---------- kernel 3 (slim): dots GEMM + loss, sim read back packed ----------
__global__ __launch_bounds__(256, 4) void phase2_kernel(
    const ushort_t* __restrict__ Ibf, const ushort_t* __restrict__ Tbf,
    const float* __restrict__ img_norm, const float* __restrict__ txt_norm,
    const unsigned* __restrict__ mn_u, const unsigned* __restrict__ mx_u,
    const int* __restrict__ instr, const ushort_t* __restrict__ simbuf,
    float* __restrict__ out) {
    __shared__ __align__(16) ushort_t Im[128 * 64];
    __shared__ __align__(16) ushort_t Tj[128 * 64];
    const int tile_j = blockIdx.x, tile_i = blockIdx.y;
    const int wave = threadIdx.x >> 6, lane = threadIdx.x & 63;
    const int wr = wave >> 1, wc = wave & 1;

    floatx4 accD[4][4];
#pragma unroll
    for (int m = 0; m < 4; m++)
#pragma unroll
        for (int n = 0; n < 4; n++) accD[m][n] = (floatx4){0.f, 0.f, 0.f, 0.f};

    for (int k0 = 0; k0 < DIM; k0 += 64) {
        __syncthreads();
        stage_tile(Ibf + (size_t)(tile_i * 128) * DIM + k0, Im, wave, lane);
        stage_tile(Tbf + (size_t)(tile_j * 128) * DIM + k0, Tj, wave, lane);
        __syncthreads();
#pragma unroll
        for (int kk = 0; kk < 2; kk++) {
            short8 ai[4], b[4];
#pragma unroll
            for (int m = 0; m < 4; m++) ai[m] = read_frag(Im, wr * 4 + m, kk, lane);
#pragma unroll
            for (int n = 0; n < 4; n++) b[n] = read_frag(Tj, wc * 4 + n, kk, lane);
#pragma unroll
            for (int m = 0; m < 4; m++)
#pragma unroll
                for (int n = 0; n < 4; n++)
                    accD[m][n] = __builtin_amdgcn_mfma_f32_16x16x32_bf16(ai[m], b[n], accD[m][n], 0, 0, 0);
        }
    }

    // epilogue: per-pair loss; sim read back in packed per-lane layout
    const int rbase0 = tile_i * 128 + wr * 64;
    const int cbase0 = tile_j * 128 + wc * 64;
    const ushort_t* sp = simbuf + (((size_t)(tile_i * 32 + tile_j) * 256 + threadIdx.x) * 64);
    float tn4[4]; int ic4[4];
#pragma unroll
    for (int n = 0; n < 4; n++) {
        int col_g = cbase0 + n * 16 + (lane & 15);
        tn4[n] = txt_norm[col_g];
        ic4[n] = instr[col_g];
    }
    float lsum = 0.f;
#pragma unroll
    for (int m = 0; m < 4; m++) {
        ushort8 s0 = reinterpret_cast<const ushort8*>(sp)[m * 2 + 0];
        ushort8 s1 = reinterpret_cast<const ushort8*>(sp)[m * 2 + 1];
        int rb = rbase0 + m * 16 + (lane >> 4) * 4;
#pragma unroll
        for (int reg = 0; reg < 4; reg++) {
            int row_g = rb + reg;
            float inr = img_norm[row_g];
            float mnv = funmap(mn_u[row_g]);
            float mxv = funmap(mx_u[row_g]);
            int   ir  = instr[row_g];
            float winv = 1.0f / (mxv - mnv + EPS_W);
#pragma unroll
            for (int n = 0; n < 4; n++) {
                int col_g = cbase0 + n * 16 + (lane & 15);
                float simv = (n < 2) ? bf2f(s0[(n & 1) * 4 + reg])
                                     : bf2f(s1[(n & 1) * 4 + reg]);
                float cosv = accD[m][n][reg] / fmaxf(inr * tn4[n], EPS_COS);
                float w = (simv - mnv) * winv;
                bool aligned = (ir == ic4[n]) || (row_g == col_g);
                lsum += aligned ? (1.0f - cosv) : fmaxf(0.0f, cosv - w);
            }
        }
    }
#pragma unroll
    for (int s = 1; s < 64; s <<= 1) lsum += __shfl_xor(lsum, s);
    if (lane == 0)
        atomicAdd(out, lsum * (1.0f / ((float)NROWS * (float)NROWS)));
}

// ---------- fallback fused kernel (round-1 phase2): used if ws too small ----------
__global__ __launch_bounds__(256) void phase2_fused_kernel(
    const ushort_t* __restrict__ Ibf, const ushort_t* __restrict__ Tbf,
    const float* __restrict__ img_norm, const float* __restrict__ txt_norm,
    const unsigned* __restrict__ mn_u, const unsigned* __restrict__ mx_u,
    const int* __restrict__ instr, float* __restrict__ out) {
    __shared__ __align__(16) ushort_t Im[128 * 64];
    __shared__ __align__(16) ushort_t Ti[128 * 64];
    __shared__ __align__(16) ushort_t Tj[128 * 64];
    const int tile_j = blockIdx.x, tile_i = blockIdx.y;
    const int wave = threadIdx.x >> 6, lane = threadIdx.x & 63;
    const int wr = wave >> 1, wc = wave & 1;

    floatx4 accD[4][4], accS[4][4];
#pragma unroll
    for (int m = 0; m < 4; m++)
#pragma unroll
        for (int n = 0; n < 4; n++) {
            accD[m][n] = (floatx4){0.f, 0.f, 0.f, 0.f};
            accS[m][n] = (floatx4){0.f, 0.f, 0.f, 0.f};
        }

    for (int k0 = 0; k0 < DIM; k0 += 64) {
        __syncthreads();
        stage_tile(Ibf + (size_t)(tile_i * 128) * DIM + k0, Im, wave, lane);
        stage_tile(Tbf + (size_t)(tile_i * 128) * DIM + k0, Ti, wave, lane);
        stage_tile(Tbf + (size_t)(tile_j * 128) * DIM + k0, Tj, wave, lane);
        __syncthreads();
#pragma unroll
        for (int kk = 0; kk < 2; kk++) {
            short8 ai[4], at[4], b[4];
#pragma unroll
            for (int m = 0; m < 4; m++) ai[m] = read_frag(Im, wr * 4 + m, kk, lane);
#pragma unroll
            for (int m = 0; m < 4; m++) at[m] = read_frag(Ti, wr * 4 + m, kk, lane);
#pragma unroll
            for (int n = 0; n < 4; n++) b[n] = read_frag(Tj, wc * 4 + n, kk, lane);
#pragma unroll
            for (int m = 0; m < 4; m++)
#pragma unroll
                for (int n = 0; n < 4; n++) {
                    accD[m][n] = __builtin_amdgcn_mfma_f32_16x16x32_bf16(ai[m], b[n], accD[m][n], 0, 0, 0);
                    accS[m][n] = __builtin_amdgcn_mfma_f32_16x16x32_bf16(at[m], b[n], accS[m][n], 0, 0, 0);
                }
        }
    }

    const int rbase0 = tile_i * 128 + wr * 64;
    const int cbase0 = tile_j * 128 + wc * 64;
    float tn4[4]; int ic4[4];
#pragma unroll
    for (int n = 0; n < 4; n++) {
        int col_g = cbase0 + n * 16 + (lane & 15);
        tn4[n] = txt_norm[col_g];
        ic4[n] = instr[col_g];
    }
    float lsum = 0.f;
#pragma unroll
    for (int m = 0; m < 4; m++) {
        int rb = rbase0 + m * 16 + (lane >> 4) * 4;
#pragma unroll
        for (int reg = 0; reg < 4; reg++) {
            int row_g = rb + reg;
            float inr = img_norm[row_g];
            float mnv = funmap(mn_u[row_g]);
            float mxv = funmap(mx_u[row_g]);
            int   ir  = instr[row_g];
            float winv = 1.0f / (mxv - mnv + EPS_W);
#pragma unroll
            for (int n = 0; n < 4; n++) {
                int col_g = cbase0 + n * 16 + (lane & 15);
                float cosv = accD[m][n][reg] / fmaxf(inr * tn4[n], EPS_COS);
                float w = (accS[m][n][reg] - mnv) * winv;
                bool aligned = (ir == ic4[n]) || (row_g == col_g);
                lsum += aligned ? (1.0f - cosv) : fmaxf(0.0f, cosv - w);
            }
        }
    }
#pragma unroll
    for (int s = 1; s < 64; s <<= 1) lsum += __shfl_xor(lsum, s);
    if (lane == 0)
        atomicAdd(out, lsum * (1.0f / ((float)NROWS * (float)NROWS)));
}

// legacy phase1 (no sim store) for fallback path
__global__ __launch_bounds__(256) void phase1_nostore_kernel(
    const ushort_t* __restrict__ Tbf,
    unsigned* __restrict__ mn_u, unsigned* __restrict__ mx_u) {
    __shared__ __align__(16) ushort_t Ti[128 * 64];
    __shared__ __align__(16) ushort_t Tj[128 * 64];
    const int tile_j = blockIdx.x, tile_i = blockIdx.y;
    const int wave = threadIdx.x >> 6, lane = threadIdx.x & 63;
    const int wr = wave >> 1, wc = wave & 1;

    floatx4 acc[4][4];
#pragma unroll
    for (int m = 0; m < 4; m++)
#pragma unroll
        for (int n = 0; n < 4; n++) acc[m][n] = (floatx4){0.f, 0.f, 0.f, 0.f};

    for (int k0 = 0; k0 < DIM; k0 += 64) {
        __syncthreads();
        stage_tile(Tbf + (size_t)(tile_i * 128) * DIM + k0, Ti, wave, lane);
        stage_tile(Tbf + (size_t)(tile_j * 128) * DIM + k0, Tj, wave, lane);
        __syncthreads();
#pragma unroll
        for (int kk = 0; kk < 2; kk++) {
            short8 a[4], b[4];
#pragma unroll
            for (int m = 0; m < 4; m++) a[m] = read_frag(Ti, wr * 4 + m, kk, lane);
#pragma unroll
            for (int n = 0; n < 4; n++) b[n] = read_frag(Tj, wc * 4 + n, kk, lane);
#pragma unroll
            for (int m = 0; m < 4; m++)
#pragma unroll
                for (int n = 0; n < 4; n++)
                    acc[m][n] = __builtin_amdgcn_mfma_f32_16x16x32_bf16(a[m], b[n], acc[m][n], 0, 0, 0);
        }
    }
#pragma unroll
    for (int m = 0; m < 4; m++) {
#pragma unroll
        for (int reg = 0; reg < 4; reg++) {
            float vmin = acc[m][0][reg], vmax = acc[m][0][reg];
#pragma unroll
            for (int n = 1; n < 4; n++) {
                vmin = fminf(vmin, acc[m][n][reg]);
                vmax = fmaxf(vmax, acc[m][n][reg]);
            }
#pragma unroll
            for (int s = 1; s < 16; s <<= 1) {
                vmin = fminf(vmin, __shfl_xor(vmin, s));
                vmax = fmaxf(vmax, __shfl_xor(vmax, s));
            }
            if ((lane & 15) == 0) {
                int row_g = tile_i * 128 + wr * 64 + m * 16 + (lane >> 4) * 4 + reg;
                atomicMin(&mn_u[row_g], fmap(vmin));
                atomicMax(&mx_u[row_g], fmap(vmax));
            }
        }
    }
}

// ---------- launch ----------
extern "C" void kernel_launch(void* const* d_in, const int* in_sizes, int n_in,
                              void* d_out, int out_size, void* d_ws, size_t ws_size,
                              hipStream_t stream) {
    const float* img = (const float*)d_in[0];
    const float* txt = (const float*)d_in[1];
    const int* instr = (const int*)d_in[2];
    float* out = (float*)d_out;

    char* ws = (char*)d_ws;
    ushort_t* Tbf = (ushort_t*)ws;                                  // 4 MB
    ushort_t* Ibf = (ushort_t*)(ws + (size_t)NROWS * DIM * 2);      // 4 MB
    float* img_norm = (float*)(ws + (size_t)NROWS * DIM * 4);       // 16 KB
    float* txt_norm = img_norm + NROWS;                             // 16 KB
    unsigned* mn_u = (unsigned*)(txt_norm + NROWS);                 // 16 KB
    unsigned* mx_u = mn_u + NROWS;                                  // 16 KB
    ushort_t* simbuf = (ushort_t*)(mx_u + NROWS);                   // 32 MB
    const size_t need = (size_t)NROWS * DIM * 4 + 4 * (size_t)NROWS * 4
                      + (size_t)NROWS * NROWS * 2;

    hipMemsetAsync(d_out, 0, sizeof(float), stream);
    prep_kernel<<<NROWS / 4, 256, 0, stream>>>(img, txt, Ibf, Tbf,
                                               img_norm, txt_norm, mn_u, mx_u);
    dim3 grid(NROWS / 128, NROWS / 128);
    if (ws_size >= need) {
        phase1_kernel<<<grid, 256, 0, stream>>>(Tbf, mn_u, mx_u, simbuf);
        phase2_kernel<<<grid, 256, 0, stream>>>(Ibf, Tbf, img_norm, txt_norm,
                                                mn_u, mx_u, instr, simbuf, out);
    } else {
        phase1_nostore_kernel<<<grid, 256, 0, stream>>>(Tbf, mn_u, mx_u);
        phase2_fused_kernel<<<grid, 256, 0, stream>>>(Ibf, Tbf, img_norm, txt_norm,
                                                      mn_u, mx_u, instr, out);
    }
}

// Round 3
// 102.582 us; speedup vs baseline: 1.4003x; 1.3946x over previous
//
#include <hip/hip_runtime.h>
#include <stdint.h>

#define NROWS 4096
#define DIM   512
#define EPS_COS 1e-8f
#define EPS_W   1e-6f
#define BT     256                 // output tile: BT x BT
#define NTILE  (NROWS / BT)        // 16
#define NKSTEP (DIM / 64)          // 8

typedef unsigned short ushort_t;
typedef __attribute__((ext_vector_type(8))) short   short8;
typedef __attribute__((ext_vector_type(8))) unsigned short ushort8;
typedef __attribute__((ext_vector_type(4))) float   floatx4;

// ---------- helpers ----------
__device__ inline ushort_t f2bf(float x) {            // RNE float->bf16
    unsigned u = __float_as_uint(x);
    unsigned r = (u + 0x7FFFu + ((u >> 16) & 1u)) >> 16;
    return (ushort_t)r;
}
__device__ inline float bf2f(ushort_t u) {
    return __uint_as_float(((unsigned)u) << 16);
}
// monotone float<->uint mapping for atomicMin/Max on floats
__device__ inline unsigned fmap(float f) {
    unsigned u = __float_as_uint(f);
    return (u & 0x80000000u) ? ~u : (u | 0x80000000u);
}
__device__ inline float funmap(unsigned u) {
    return __uint_as_float((u & 0x80000000u) ? (u & 0x7fffffffu) : ~u);
}

__device__ inline void gload_lds16(const void* g, void* l) {
    auto* gp = reinterpret_cast<const __attribute__((address_space(1))) unsigned int*>(
        reinterpret_cast<uintptr_t>(g));
    auto* lp = reinterpret_cast<__attribute__((address_space(3))) unsigned int*>(
        reinterpret_cast<uintptr_t>(l));
    __builtin_amdgcn_global_load_lds(gp, lp, 16, 0, 0);
}

// stage a 256x64 bf16 tile with 8 waves (512 threads):
// linear LDS dest + inverse-swizzled global source.
// LDS[r][c_phys] holds logical chunk c_phys ^ (r&7)  (chunk = 16B = 8 bf16)
__device__ inline void stage_tile(const ushort_t* __restrict__ gbase, // tile row0 + k0 applied
                                  ushort_t* lds, int wave, int lane) {
#pragma unroll
    for (int q = 0; q < 4; q++) {
        int row0 = wave * 32 + q * 8;                 // multiple of 8; 8 waves cover 256 rows
        int lrow = row0 + (lane >> 3);
        int src_chunk = (lane & 7) ^ (lane >> 3);     // (lane&7) ^ (lrow&7)
        const ushort_t* g = gbase + (size_t)lrow * DIM + src_chunk * 8;
        gload_lds16(g, lds + row0 * 64);              // wave-uniform base; HW adds lane*16
    }
}

// fragment read: lane l -> row = frag_row*16 + (l&15), logical chunk = kk*4 + (l>>4),
// phys chunk = logical ^ (row&7)
__device__ inline short8 read_frag(const ushort_t* tile, int frag_row, int kk, int lane) {
    int r = frag_row * 16 + (lane & 15);
    int c = (kk * 4 + (lane >> 4)) ^ (lane & 7);
    return *reinterpret_cast<const short8*>(tile + r * 64 + c * 8);
}

// ---------- kernel 1: convert + norms + init ----------
__global__ __launch_bounds__(256) void prep_kernel(
    const float* __restrict__ img, const float* __restrict__ txt,
    ushort_t* __restrict__ Ibf, ushort_t* __restrict__ Tbf,
    float* __restrict__ img_norm, float* __restrict__ txt_norm,
    unsigned* __restrict__ mn_u, unsigned* __restrict__ mx_u) {
    const int wave = threadIdx.x >> 6, lane = threadIdx.x & 63;
    const int row = blockIdx.x * 4 + wave;
    const int col0 = lane * 8;
    {
        const float4* p = reinterpret_cast<const float4*>(img + (size_t)row * DIM + col0);
        float4 a = p[0], b = p[1];
        float ss = a.x*a.x + a.y*a.y + a.z*a.z + a.w*a.w
                 + b.x*b.x + b.y*b.y + b.z*b.z + b.w*b.w;
        ushort8 o;
        o[0]=f2bf(a.x); o[1]=f2bf(a.y); o[2]=f2bf(a.z); o[3]=f2bf(a.w);
        o[4]=f2bf(b.x); o[5]=f2bf(b.y); o[6]=f2bf(b.z); o[7]=f2bf(b.w);
        *reinterpret_cast<ushort8*>(Ibf + (size_t)row * DIM + col0) = o;
#pragma unroll
        for (int s = 1; s < 64; s <<= 1) ss += __shfl_xor(ss, s);
        if (lane == 0) img_norm[row] = sqrtf(ss);
    }
    {
        const float4* p = reinterpret_cast<const float4*>(txt + (size_t)row * DIM + col0);
        float4 a = p[0], b = p[1];
        float ss = a.x*a.x + a.y*a.y + a.z*a.z + a.w*a.w
                 + b.x*b.x + b.y*b.y + b.z*b.z + b.w*b.w;
        ushort8 o;
        o[0]=f2bf(a.x); o[1]=f2bf(a.y); o[2]=f2bf(a.z); o[3]=f2bf(a.w);
        o[4]=f2bf(b.x); o[5]=f2bf(b.y); o[6]=f2bf(b.z); o[7]=f2bf(b.w);
        *reinterpret_cast<ushort8*>(Tbf + (size_t)row * DIM + col0) = o;
#pragma unroll
        for (int s = 1; s < 64; s <<= 1) ss += __shfl_xor(ss, s);
        if (lane == 0) txt_norm[row] = sqrtf(ss);
    }
    if (lane == 0) { mn_u[row] = 0xFFFFFFFFu; mx_u[row] = 0u; }
}

// ---------- kernel 2: T.T^T -> row min/max atomics + packed bf16 sim store ----------
// 256x256 tile, 8 waves; per-wave output 128x64 (wr=wave>>2 in {0,1}, wc=wave&3).
// Single barrier per K-step; next tile prefetched into buf^1 BEFORE compute so the
// barrier's vmcnt(0) drain lands after ~1k cycles of MFMA/ds_read cover L2 latency.
// sim stored PER-LANE-PACKED (128 bf16/thread): element idx = m*16 + n*4 + reg.
__global__ __launch_bounds__(512, 2) void phase1_kernel(
    const ushort_t* __restrict__ Tbf,
    unsigned* __restrict__ mn_u, unsigned* __restrict__ mx_u,
    ushort_t* __restrict__ simbuf) {
    __shared__ __align__(16) ushort_t Ta[2][BT * 64];   // 64 KB
    __shared__ __align__(16) ushort_t Tb[2][BT * 64];   // 64 KB
    const int tile_j = blockIdx.x, tile_i = blockIdx.y;
    const int tid = threadIdx.x;
    const int wave = tid >> 6, lane = tid & 63;
    const int wr = wave >> 2, wc = wave & 3;
    const ushort_t* gA = Tbf + (size_t)(tile_i * BT) * DIM;
    const ushort_t* gB = Tbf + (size_t)(tile_j * BT) * DIM;

    floatx4 acc[8][4];
#pragma unroll
    for (int m = 0; m < 8; m++)
#pragma unroll
        for (int n = 0; n < 4; n++) acc[m][n] = (floatx4){0.f, 0.f, 0.f, 0.f};

    stage_tile(gA, Ta[0], wave, lane);
    stage_tile(gB, Tb[0], wave, lane);
    __syncthreads();
    int cur = 0;
    for (int t = 0; t < NKSTEP; t++) {
        if (t + 1 < NKSTEP) {                          // prefetch next K-tile first
            stage_tile(gA + (t + 1) * 64, Ta[cur ^ 1], wave, lane);
            stage_tile(gB + (t + 1) * 64, Tb[cur ^ 1], wave, lane);
        }
#pragma unroll
        for (int kk = 0; kk < 2; kk++) {
            short8 a[8], b[4];
#pragma unroll
            for (int m = 0; m < 8; m++) a[m] = read_frag(Ta[cur], wr * 8 + m, kk, lane);
#pragma unroll
            for (int n = 0; n < 4; n++) b[n] = read_frag(Tb[cur], wc * 4 + n, kk, lane);
#pragma unroll
            for (int m = 0; m < 8; m++)
#pragma unroll
                for (int n = 0; n < 4; n++)
                    acc[m][n] = __builtin_amdgcn_mfma_f32_16x16x32_bf16(a[m], b[n], acc[m][n], 0, 0, 0);
        }
        __syncthreads();
        cur ^= 1;
    }

    // per-row min/max (fp32-exact); rows = tile_i*256 + wr*128 + m*16 + (l>>4)*4 + reg
#pragma unroll
    for (int m = 0; m < 8; m++) {
#pragma unroll
        for (int reg = 0; reg < 4; reg++) {
            float vmin = acc[m][0][reg], vmax = acc[m][0][reg];
#pragma unroll
            for (int n = 1; n < 4; n++) {
                vmin = fminf(vmin, acc[m][n][reg]);
                vmax = fmaxf(vmax, acc[m][n][reg]);
            }
#pragma unroll
            for (int s = 1; s < 16; s <<= 1) {
                vmin = fminf(vmin, __shfl_xor(vmin, s));
                vmax = fmaxf(vmax, __shfl_xor(vmax, s));
            }
            if ((lane & 15) == 0) {
                int row_g = tile_i * BT + wr * 128 + m * 16 + (lane >> 4) * 4 + reg;
                atomicMin(&mn_u[row_g], fmap(vmin));
                atomicMax(&mx_u[row_g], fmap(vmax));
            }
        }
    }

    // packed bf16 store of the sim tile (16 x 16B per lane, coalesced)
    ushort_t* sp = simbuf + (((size_t)(tile_i * NTILE + tile_j) * 512 + tid) * 128);
#pragma unroll
    for (int c = 0; c < 16; c++) {
        int m = c >> 1, n0 = (c & 1) * 2;
        ushort8 o;
        o[0] = f2bf(acc[m][n0][0]);     o[1] = f2bf(acc[m][n0][1]);
        o[2] = f2bf(acc[m][n0][2]);     o[3] = f2bf(acc[m][n0][3]);
        o[4] = f2bf(acc[m][n0 + 1][0]); o[5] = f2bf(acc[m][n0 + 1][1]);
        o[6] = f2bf(acc[m][n0 + 1][2]); o[7] = f2bf(acc[m][n0 + 1][3]);
        reinterpret_cast<ushort8*>(sp)[c] = o;
    }
}

// ---------- kernel 3: dots GEMM + loss; sim read back packed ----------
__global__ __launch_bounds__(512, 2) void phase2_kernel(
    const ushort_t* __restrict__ Ibf, const ushort_t* __restrict__ Tbf,
    const float* __restrict__ img_norm, const float* __restrict__ txt_norm,
    const unsigned* __restrict__ mn_u, const unsigned* __restrict__ mx_u,
    const int* __restrict__ instr, const ushort_t* __restrict__ simbuf,
    float* __restrict__ out) {
    __shared__ __align__(16) ushort_t Ta[2][BT * 64];
    __shared__ __align__(16) ushort_t Tb[2][BT * 64];
    const int tile_j = blockIdx.x, tile_i = blockIdx.y;
    const int tid = threadIdx.x;
    const int wave = tid >> 6, lane = tid & 63;
    const int wr = wave >> 2, wc = wave & 3;
    const ushort_t* gA = Ibf + (size_t)(tile_i * BT) * DIM;
    const ushort_t* gB = Tbf + (size_t)(tile_j * BT) * DIM;

    floatx4 acc[8][4];
#pragma unroll
    for (int m = 0; m < 8; m++)
#pragma unroll
        for (int n = 0; n < 4; n++) acc[m][n] = (floatx4){0.f, 0.f, 0.f, 0.f};

    stage_tile(gA, Ta[0], wave, lane);
    stage_tile(gB, Tb[0], wave, lane);
    __syncthreads();
    int cur = 0;
    for (int t = 0; t < NKSTEP; t++) {
        if (t + 1 < NKSTEP) {
            stage_tile(gA + (t + 1) * 64, Ta[cur ^ 1], wave, lane);
            stage_tile(gB + (t + 1) * 64, Tb[cur ^ 1], wave, lane);
        }
#pragma unroll
        for (int kk = 0; kk < 2; kk++) {
            short8 a[8], b[4];
#pragma unroll
            for (int m = 0; m < 8; m++) a[m] = read_frag(Ta[cur], wr * 8 + m, kk, lane);
#pragma unroll
            for (int n = 0; n < 4; n++) b[n] = read_frag(Tb[cur], wc * 4 + n, kk, lane);
#pragma unroll
            for (int m = 0; m < 8; m++)
#pragma unroll
                for (int n = 0; n < 4; n++)
                    acc[m][n] = __builtin_amdgcn_mfma_f32_16x16x32_bf16(a[m], b[n], acc[m][n], 0, 0, 0);
        }
        __syncthreads();
        cur ^= 1;
    }

    // epilogue: per-pair loss; sim read back in packed per-lane layout
    const int rbase0 = tile_i * BT + wr * 128;
    const int cbase0 = tile_j * BT + wc * 64;
    const ushort_t* sp = simbuf + (((size_t)(tile_i * NTILE + tile_j) * 512 + tid) * 128);
    float tn4[4]; int ic4[4];
#pragma unroll
    for (int n = 0; n < 4; n++) {
        int col_g = cbase0 + n * 16 + (lane & 15);
        tn4[n] = txt_norm[col_g];
        ic4[n] = instr[col_g];
    }
    float lsum = 0.f;
#pragma unroll
    for (int m = 0; m < 8; m++) {
        ushort8 s0 = reinterpret_cast<const ushort8*>(sp)[m * 2 + 0];
        ushort8 s1 = reinterpret_cast<const ushort8*>(sp)[m * 2 + 1];
        int rb = rbase0 + m * 16 + (lane >> 4) * 4;
#pragma unroll
        for (int reg = 0; reg < 4; reg++) {
            int row_g = rb + reg;
            float inr = img_norm[row_g];
            float mnv = funmap(mn_u[row_g]);
            float mxv = funmap(mx_u[row_g]);
            int   ir  = instr[row_g];
            float winv = 1.0f / (mxv - mnv + EPS_W);
#pragma unroll
            for (int n = 0; n < 4; n++) {
                int col_g = cbase0 + n * 16 + (lane & 15);
                float simv = (n < 2) ? bf2f(s0[(n & 1) * 4 + reg])
                                     : bf2f(s1[(n & 1) * 4 + reg]);
                float cosv = acc[m][n][reg] / fmaxf(inr * tn4[n], EPS_COS);
                float w = (simv - mnv) * winv;
                bool aligned = (ir == ic4[n]) || (row_g == col_g);
                lsum += aligned ? (1.0f - cosv) : fmaxf(0.0f, cosv - w);
            }
        }
    }
#pragma unroll
    for (int s = 1; s < 64; s <<= 1) lsum += __shfl_xor(lsum, s);
    if (lane == 0)
        atomicAdd(out, lsum * (1.0f / ((float)NROWS * (float)NROWS)));
}

// ---------- launch ----------
extern "C" void kernel_launch(void* const* d_in, const int* in_sizes, int n_in,
                              void* d_out, int out_size, void* d_ws, size_t ws_size,
                              hipStream_t stream) {
    const float* img = (const float*)d_in[0];
    const float* txt = (const float*)d_in[1];
    const int* instr = (const int*)d_in[2];
    float* out = (float*)d_out;

    char* ws = (char*)d_ws;
    ushort_t* Tbf = (ushort_t*)ws;                                  // 4 MB
    ushort_t* Ibf = (ushort_t*)(ws + (size_t)NROWS * DIM * 2);      // 4 MB
    float* img_norm = (float*)(ws + (size_t)NROWS * DIM * 4);       // 16 KB
    float* txt_norm = img_norm + NROWS;                             // 16 KB
    unsigned* mn_u = (unsigned*)(txt_norm + NROWS);                 // 16 KB
    unsigned* mx_u = mn_u + NROWS;                                  // 16 KB
    ushort_t* simbuf = (ushort_t*)(mx_u + NROWS);                   // 32 MB

    hipMemsetAsync(d_out, 0, sizeof(float), stream);
    prep_kernel<<<NROWS / 4, 256, 0, stream>>>(img, txt, Ibf, Tbf,
                                               img_norm, txt_norm, mn_u, mx_u);
    dim3 grid(NTILE, NTILE);   // 16 x 16 = 256 blocks = 1 per CU
    phase1_kernel<<<grid, 512, 0, stream>>>(Tbf, mn_u, mx_u, simbuf);
    phase2_kernel<<<grid, 512, 0, stream>>>(Ibf, Tbf, img_norm, txt_norm,
                                            mn_u, mx_u, instr, simbuf, out);
}